// Round 15
// baseline (552.468 us; speedup 1.0000x reference)
//
#include <hip/hip_runtime.h>
#include <hip/hip_bf16.h>

#define HID 256
#define NN 8192
#define NE 262144

typedef float f32x4 __attribute__((ext_vector_type(4)));
typedef __bf16 bf16x8 __attribute__((ext_vector_type(8)));
typedef __bf16 bf16x4 __attribute__((ext_vector_type(4)));

// ---------------- weight conversion: f32 -> bf16, [Wq][Wk][Wv][We] ----------------
__global__ void conv_weights(const float* __restrict__ wq, const float* __restrict__ wk,
                             const float* __restrict__ wv, const float* __restrict__ we,
                             __bf16* __restrict__ o) {
    int i = blockIdx.x * 256 + threadIdx.x;
    const float* srcs[4] = {wq, wk, wv, we};
    int m = i >> 16;
    int j = i & 65535;
    o[i] = (__bf16)srcs[m][j];
}

// ---------------- bulk f32 -> bf16 (8 elems/thread, grid-stride) ------------------
__global__ void conv_bf16(const float* __restrict__ in, __bf16* __restrict__ out, int n8) {
    for (int i = blockIdx.x * 256 + threadIdx.x; i < n8; i += gridDim.x * 256) {
        float4 a = ((const float4*)in)[i * 2];
        float4 b = ((const float4*)in)[i * 2 + 1];
        bf16x8 h;
        h[0] = (__bf16)a.x; h[1] = (__bf16)a.y; h[2] = (__bf16)a.z; h[3] = (__bf16)a.w;
        h[4] = (__bf16)b.x; h[5] = (__bf16)b.y; h[6] = (__bf16)b.z; h[7] = (__bf16)b.w;
        ((bf16x8*)out)[i] = h;
    }
}

// ------- QKV projection: no LDS, MFMA B-operand loads directly from global xb -----
__global__ __launch_bounds__(256, 4)
void qkv_gemm(const __bf16* __restrict__ xb,
              const __bf16* __restrict__ wbf,
              const float* __restrict__ bq, const float* __restrict__ bk,
              const float* __restrict__ bv,
              __bf16* __restrict__ qbf, __bf16* __restrict__ kbf,
              __bf16* __restrict__ vbf) {
    int tid = threadIdx.x;
    int blk = blockIdx.x;
    int m = blockIdx.y;

    int w = tid >> 6, lane = tid & 63;
    int l15 = lane & 15, l4 = lane >> 4;
    int cw = w * 64;
    const float* bias = (m == 0) ? bq : ((m == 1) ? bk : bv);
    __bf16* out = (m == 0) ? qbf : ((m == 1) ? kbf : vbf);

    const __bf16* W = wbf + (size_t)m * 65536;
    f32x4 acc[4][2] = {};
    #pragma unroll
    for (int ks = 0; ks < 8; ++ks) {
        bf16x8 aW[4], bE[2];
        #pragma unroll
        for (int tn = 0; tn < 4; ++tn)
            aW[tn] = *(const bf16x8*)(W + (size_t)(cw + tn * 16 + l15) * 256 + ks * 32 + l4 * 8);
        #pragma unroll
        for (int te = 0; te < 2; ++te)
            bE[te] = *(const bf16x8*)(xb + (size_t)(blk * 32 + te * 16 + l15) * 256 + ks * 32 + l4 * 8);
        #pragma unroll
        for (int tn = 0; tn < 4; ++tn)
            #pragma unroll
            for (int te = 0; te < 2; ++te)
                acc[tn][te] = __builtin_amdgcn_mfma_f32_16x16x32_bf16(aW[tn], bE[te], acc[tn][te], 0, 0, 0);
    }
    #pragma unroll
    for (int tn = 0; tn < 4; ++tn) {
        float4 b4 = *(const float4*)(bias + cw + tn * 16 + l4 * 4);
        #pragma unroll
        for (int te = 0; te < 2; ++te) {
            int row = blk * 32 + te * 16 + l15;
            int col = cw + tn * 16 + l4 * 4;
            bf16x4 h;
            h[0] = (__bf16)(acc[tn][te][0] + b4.x);
            h[1] = (__bf16)(acc[tn][te][1] + b4.y);
            h[2] = (__bf16)(acc[tn][te][2] + b4.z);
            h[3] = (__bf16)(acc[tn][te][3] + b4.w);
            *(bf16x4*)(out + (size_t)row * 256 + col) = h;
        }
    }
}

// ---------------- counting sort by destination key = b*NN + s ---------------------
__global__ void k_hist(const int* __restrict__ eidx, unsigned* __restrict__ hist) {
    int e = blockIdx.x * 256 + threadIdx.x;
    int key = eidx[e] * NN + eidx[NE + e];
    atomicAdd(&hist[key], 1u);
}

__global__ void k_scan(const unsigned* __restrict__ hist, unsigned* __restrict__ cursor) {
    __shared__ unsigned tot[256];
    int tid = threadIdx.x;
    unsigned s = 0;
    for (int i = 0; i < 64; ++i) s += hist[tid * 64 + i];
    tot[tid] = s;
    __syncthreads();
    for (int d = 1; d < 256; d <<= 1) {
        unsigned v = (tid >= d) ? tot[tid - d] : 0u;
        __syncthreads();
        tot[tid] += v;
        __syncthreads();
    }
    unsigned run = (tid == 0) ? 0u : tot[tid - 1];
    for (int i = 0; i < 64; ++i) {
        int idx = tid * 64 + i;
        cursor[idx] = run;
        run += hist[idx];
    }
}

__global__ void k_perm(const int* __restrict__ eidx, unsigned* __restrict__ cursor,
                       int* __restrict__ perm) {
    int e = blockIdx.x * 256 + threadIdx.x;
    int key = eidx[e] * NN + eidx[NE + e];
    unsigned pos = atomicAdd(&cursor[key], 1u);
    perm[pos] = e;
}

// ------- edge logits: direct-global MFMA B (evb), one barrier ---------------------
__global__ __launch_bounds__(512, 4)
void edge_logits(const __bf16* __restrict__ evb,
                 const int* __restrict__ eidx,
                 const __bf16* __restrict__ wbf,
                 const float* __restrict__ bkb,
                 const __bf16* __restrict__ qbf, const __bf16* __restrict__ kbf,
                 float* __restrict__ attn_ws) {
    __shared__ __bf16 ket[64 * 256];   // Ke tile (32 KB)
    __shared__ int sb[64], ss[64], st[64];
    char* lb = (char*)ket;
    int tid = threadIdx.x;
    int e0 = blockIdx.x * 64;

    if (tid < 64) {
        sb[tid] = eidx[e0 + tid];
        ss[tid] = eidx[NE + e0 + tid];
        st[tid] = eidx[2 * NE + e0 + tid];
    }

    int w = tid >> 6, lane = tid & 63;   // w in 0..7
    int l15 = lane & 15, l4 = lane >> 4;
    int cw = w * 32;

    // Ke = ev @ Wk^T -- B fragments straight from global bf16 ev (full-line reads)
    const __bf16* WK = wbf + 65536;
    f32x4 acc[2][4] = {};
    #pragma unroll
    for (int ks = 0; ks < 8; ++ks) {
        bf16x8 aW[2], bE[4];
        #pragma unroll
        for (int tn = 0; tn < 2; ++tn)
            aW[tn] = *(const bf16x8*)(WK + (size_t)(cw + tn * 16 + l15) * 256 + ks * 32 + l4 * 8);
        #pragma unroll
        for (int te = 0; te < 4; ++te)
            bE[te] = *(const bf16x8*)(evb + (size_t)(e0 + te * 16 + l15) * 256 + ks * 32 + l4 * 8);
        #pragma unroll
        for (int tn = 0; tn < 2; ++tn)
            #pragma unroll
            for (int te = 0; te < 4; ++te)
                acc[tn][te] = __builtin_amdgcn_mfma_f32_16x16x32_bf16(aW[tn], bE[te], acc[tn][te], 0, 0, 0);
    }

    // Ke (+bias) -> LDS bf16, edge-swizzled
    #pragma unroll
    for (int tn = 0; tn < 2; ++tn) {
        float4 b4 = *(const float4*)(bkb + cw + tn * 16 + l4 * 4);
        #pragma unroll
        for (int te = 0; te < 4; ++te) {
            int edge = te * 16 + l15;
            int colb = (cw + tn * 16 + l4 * 4) * 2;
            bf16x4 h;
            h[0] = (__bf16)(acc[tn][te][0] + b4.x);
            h[1] = (__bf16)(acc[tn][te][1] + b4.y);
            h[2] = (__bf16)(acc[tn][te][2] + b4.z);
            h[3] = (__bf16)(acc[tn][te][3] + b4.w);
            int off = (edge * 512 + colb) ^ ((edge & 7) << 4);
            *(bf16x4*)(lb + off) = h;
        }
    }
    __syncthreads();   // Ke + idx visible

    // logits + softmax; half-wave per edge, 8 edges per wave
    int cl = lane & 31, eh = lane >> 5;
    #pragma unroll
    for (int it = 0; it < 4; ++it) {
        int e = w * 8 + it * 2 + eh;
        int b_ = sb[e], s_ = ss[e], t_ = st[e];
        bf16x8 qv = *(const bf16x8*)(qbf + ((size_t)b_ * NN + s_) * 256 + cl * 8);
        bf16x8 kv = *(const bf16x8*)(kbf + ((size_t)b_ * NN + t_) * 256 + cl * 8);
        int off = (e * 512 + cl * 16) ^ ((e & 7) << 4);
        bf16x8 kev = *(const bf16x8*)(lb + off);
        float val = 0.f;
        #pragma unroll
        for (int j = 0; j < 8; ++j)
            val += (float)qv[j] * ((float)kv[j] + (float)kev[j]);
        val += __shfl_xor(val, 1);
        val += __shfl_xor(val, 2);          // 4-lane group = one head (D=32)
        val *= 0.17677669529663687f;
        float mx = val;
        mx = fmaxf(mx, __shfl_xor(mx, 4));
        mx = fmaxf(mx, __shfl_xor(mx, 8));
        mx = fmaxf(mx, __shfl_xor(mx, 16));
        float ex = __expf(val - mx);
        float s4 = ex;
        s4 += __shfl_xor(s4, 4);
        s4 += __shfl_xor(s4, 8);
        s4 += __shfl_xor(s4, 16);           // butterfly hits each head exactly once
        float a = ex / s4;
        if ((cl & 3) == 0)
            attn_ws[(size_t)(e0 + e) * 8 + (cl >> 2)] = a;
    }
}

// ------- edge scatter: sorted, direct-global MFMA B via perm, run-length tail -----
__global__ __launch_bounds__(512, 4)
void edge_scatter2(const __bf16* __restrict__ evb,
                   const int* __restrict__ eidx,
                   const __bf16* __restrict__ wbf,
                   const float* __restrict__ beb,
                   const __bf16* __restrict__ vbf,
                   const float* __restrict__ attn_ws,
                   const int* __restrict__ perm,
                   float* __restrict__ out) {
    __shared__ __bf16 vet[64 * 256];   // Ve tile (32 KB)
    __shared__ int pe[64], sb[64], ss[64], st[64];
    char* lb = (char*)vet;
    int tid = threadIdx.x;
    int p0 = blockIdx.x * 64;

    if (tid < 64) {
        int e = perm[p0 + tid];
        pe[tid] = e;
        sb[tid] = eidx[e];
        ss[tid] = eidx[NE + e];
        st[tid] = eidx[2 * NE + e];
    }
    __syncthreads();   // pe needed for B addresses

    int w = tid >> 6, lane = tid & 63;
    int l15 = lane & 15, l4 = lane >> 4;
    int cw = w * 32;

    // Ve = ev @ We^T -- B fragments straight from global bf16 ev (gathered rows)
    const __bf16* WE = wbf + 3 * 65536;
    f32x4 acc[2][4] = {};
    #pragma unroll
    for (int ks = 0; ks < 8; ++ks) {
        bf16x8 aW[2], bE[4];
        #pragma unroll
        for (int tn = 0; tn < 2; ++tn)
            aW[tn] = *(const bf16x8*)(WE + (size_t)(cw + tn * 16 + l15) * 256 + ks * 32 + l4 * 8);
        #pragma unroll
        for (int te = 0; te < 4; ++te)
            bE[te] = *(const bf16x8*)(evb + (size_t)pe[te * 16 + l15] * 256 + ks * 32 + l4 * 8);
        #pragma unroll
        for (int tn = 0; tn < 2; ++tn)
            #pragma unroll
            for (int te = 0; te < 4; ++te)
                acc[tn][te] = __builtin_amdgcn_mfma_f32_16x16x32_bf16(aW[tn], bE[te], acc[tn][te], 0, 0, 0);
    }

    // Ve (+bias) -> LDS bf16, edge-swizzled
    #pragma unroll
    for (int tn = 0; tn < 2; ++tn) {
        float4 b4 = *(const float4*)(beb + cw + tn * 16 + l4 * 4);
        #pragma unroll
        for (int te = 0; te < 4; ++te) {
            int edge = te * 16 + l15;
            int colb = (cw + tn * 16 + l4 * 4) * 2;
            bf16x4 h;
            h[0] = (__bf16)(acc[tn][te][0] + b4.x);
            h[1] = (__bf16)(acc[tn][te][1] + b4.y);
            h[2] = (__bf16)(acc[tn][te][2] + b4.z);
            h[3] = (__bf16)(acc[tn][te][3] + b4.w);
            int off = (edge * 512 + colb) ^ ((edge & 7) << 4);
            *(bf16x4*)(lb + off) = h;
        }
    }
    __syncthreads();

    // wave-per-edge tail; 8 sorted edges/wave; run-length accumulate in regs
    float a0 = 0.f, a1 = 0.f, a2 = 0.f, a3 = 0.f;
    int havekey = -1;
    size_t obase = 0;
    #pragma unroll
    for (int it = 0; it < 8; ++it) {
        int e = w * 8 + it;
        int ge = pe[e];
        int b_ = sb[e], s_ = ss[e], t_ = st[e];
        const __bf16* vrow = vbf + ((size_t)b_ * NN + t_) * 256;
        const float* arow = attn_ws + (size_t)ge * 8;
        int swz = (e & 7) << 4;
        float c0, c1, c2, c3;
        {
            float att, vv, vev;
            int col, off;
            col = lane;             att = arow[0 + (lane >> 5)];
            vv = (float)vrow[col];  off = (e * 512 + col * 2) ^ swz;
            vev = (float)*(const __bf16*)(lb + off); c0 = att * (vv + vev);
            col = 64 + lane;        att = arow[2 + (lane >> 5)];
            vv = (float)vrow[col];  off = (e * 512 + col * 2) ^ swz;
            vev = (float)*(const __bf16*)(lb + off); c1 = att * (vv + vev);
            col = 128 + lane;       att = arow[4 + (lane >> 5)];
            vv = (float)vrow[col];  off = (e * 512 + col * 2) ^ swz;
            vev = (float)*(const __bf16*)(lb + off); c2 = att * (vv + vev);
            col = 192 + lane;       att = arow[6 + (lane >> 5)];
            vv = (float)vrow[col];  off = (e * 512 + col * 2) ^ swz;
            vev = (float)*(const __bf16*)(lb + off); c3 = att * (vv + vev);
        }
        int key = __builtin_amdgcn_readfirstlane(b_ * NN + s_);
        if (key != havekey) {
            if (havekey >= 0) {
                float* orow = out + obase;
                unsafeAtomicAdd(orow + lane, a0);
                unsafeAtomicAdd(orow + 64 + lane, a1);
                unsafeAtomicAdd(orow + 128 + lane, a2);
                unsafeAtomicAdd(orow + 192 + lane, a3);
            }
            a0 = c0; a1 = c1; a2 = c2; a3 = c3;
            havekey = key;
            obase = (size_t)key * 256;
        } else {
            a0 += c0; a1 += c1; a2 += c2; a3 += c3;
        }
    }
    if (havekey >= 0) {
        float* orow = out + obase;
        unsafeAtomicAdd(orow + lane, a0);
        unsafeAtomicAdd(orow + 64 + lane, a1);
        unsafeAtomicAdd(orow + 128 + lane, a2);
        unsafeAtomicAdd(orow + 192 + lane, a3);
    }
}

extern "C" void kernel_launch(void* const* d_in, const int* in_sizes, int n_in,
                              void* d_out, int out_size, void* d_ws, size_t ws_size,
                              hipStream_t stream) {
    const float* node_states = (const float*)d_in[0];
    const int*   eidx        = (const int*)d_in[1];
    const float* ev          = (const float*)d_in[2];
    const float* Wq          = (const float*)d_in[3];
    const float* bq          = (const float*)d_in[4];
    const float* Wk          = (const float*)d_in[5];
    const float* bk          = (const float*)d_in[6];
    const float* Wv          = (const float*)d_in[7];
    const float* bv          = (const float*)d_in[8];
    const float* We          = (const float*)d_in[9];
    const float* be          = (const float*)d_in[10];
    float* out = (float*)d_out;

    char* ws = (char*)d_ws;
    __bf16*   qbf     = (__bf16*)ws;                    // 8.39 MB
    __bf16*   kbf     = (__bf16*)(ws + 8388608);        // 8.39 MB
    __bf16*   vbf     = (__bf16*)(ws + 16777216);       // 8.39 MB
    float*    attn_ws = (float*)(ws + 25165824);        // 8.39 MB
    __bf16*   wbf     = (__bf16*)(ws + 33554432);       // 0.5 MB
    unsigned* hist    = (unsigned*)(ws + 34078720);     // 64 KB
    unsigned* cursor  = (unsigned*)(ws + 34144256);     // 64 KB
    int*      perm    = (int*)(ws + 34209792);          // 1 MB
    __bf16*   evb     = (__bf16*)(ws + 35258368);       // 134.2 MB
    __bf16*   xb      = (__bf16*)(ws + 169476096);      // 8.39 MB  (total ~178 MB < ws)

    hipMemsetAsync(d_out, 0, (size_t)out_size * sizeof(float), stream);
    hipMemsetAsync(hist, 0, 16384 * sizeof(unsigned), stream);
    conv_weights<<<1024, 256, 0, stream>>>(Wq, Wk, Wv, We, wbf);
    conv_bf16<<<4096, 256, 0, stream>>>(ev, evb, NE * 256 / 8);
    conv_bf16<<<2048, 256, 0, stream>>>(node_states, xb, 2 * NN * 256 / 8);
    qkv_gemm<<<dim3(512, 3), 256, 0, stream>>>(xb, wbf, bq, bk, bv, qbf, kbf, vbf);
    k_hist<<<1024, 256, 0, stream>>>(eidx, hist);
    k_scan<<<1, 256, 0, stream>>>(hist, cursor);
    k_perm<<<1024, 256, 0, stream>>>(eidx, cursor, perm);
    edge_logits<<<4096, 512, 0, stream>>>(evb, eidx, wbf, bk, qbf, kbf, attn_ws);
    edge_scatter2<<<4096, 512, 0, stream>>>(evb, eidx, wbf, be, vbf, attn_ws, perm, out);
}

// Round 16
// 313.047 us; speedup vs baseline: 1.7648x; 1.7648x over previous
//
#include <hip/hip_runtime.h>
#include <hip/hip_bf16.h>

#define HID 256
#define NN 8192
#define NE 262144

typedef float f32x4 __attribute__((ext_vector_type(4)));
typedef __bf16 bf16x8 __attribute__((ext_vector_type(8)));
typedef __bf16 bf16x4 __attribute__((ext_vector_type(4)));

// ---------------- weight conversion: f32 -> bf16, [Wq][Wk][Wv][We] ----------------
__global__ void conv_weights(const float* __restrict__ wq, const float* __restrict__ wk,
                             const float* __restrict__ wv, const float* __restrict__ we,
                             __bf16* __restrict__ o) {
    int i = blockIdx.x * 256 + threadIdx.x;
    const float* srcs[4] = {wq, wk, wv, we};
    int m = i >> 16;
    int j = i & 65535;
    o[i] = (__bf16)srcs[m][j];
}

// ---------------- QKV projection: 32-row tiles, blockIdx.y = which GEMM -----------
__global__ __launch_bounds__(256, 6)
void qkv_gemm(const float* __restrict__ x,
              const __bf16* __restrict__ wbf,
              const float* __restrict__ bq, const float* __restrict__ bk,
              const float* __restrict__ bv,
              __bf16* __restrict__ qbf, __bf16* __restrict__ kbf,
              __bf16* __restrict__ vbf) {
    __shared__ __bf16 xt[32 * 256];
    char* lb = (char*)xt;
    int tid = threadIdx.x;
    int blk = blockIdx.x;
    int m = blockIdx.y;

    const float4* xs = (const float4*)(x + (size_t)blk * 32 * 256);
    #pragma unroll
    for (int kq = 0; kq < 8; ++kq) {
        int f = tid + kq * 256;
        int row = f >> 6, c4 = f & 63;
        float4 v = xs[f];
        bf16x4 h;
        h[0] = (__bf16)v.x; h[1] = (__bf16)v.y; h[2] = (__bf16)v.z; h[3] = (__bf16)v.w;
        int off = (row * 512 + c4 * 8) ^ ((row & 7) << 4);
        *(bf16x4*)(lb + off) = h;
    }
    __syncthreads();

    int w = tid >> 6, lane = tid & 63;
    int l15 = lane & 15, l4 = lane >> 4;
    int cw = w * 64;
    const float* bias = (m == 0) ? bq : ((m == 1) ? bk : bv);
    __bf16* out = (m == 0) ? qbf : ((m == 1) ? kbf : vbf);

    const __bf16* W = wbf + (size_t)m * 65536;
    f32x4 acc[4][2] = {};
    for (int ks = 0; ks < 8; ++ks) {
        bf16x8 aW[4], bE[2];
        #pragma unroll
        for (int tn = 0; tn < 4; ++tn)
            aW[tn] = *(const bf16x8*)(W + (size_t)(cw + tn * 16 + l15) * 256 + ks * 32 + l4 * 8);
        #pragma unroll
        for (int te = 0; te < 2; ++te) {
            int row = te * 16 + l15;
            int off = (row * 512 + ks * 64 + l4 * 16) ^ ((row & 7) << 4);
            bE[te] = *(const bf16x8*)(lb + off);
        }
        #pragma unroll
        for (int tn = 0; tn < 4; ++tn)
            #pragma unroll
            for (int te = 0; te < 2; ++te)
                acc[tn][te] = __builtin_amdgcn_mfma_f32_16x16x32_bf16(aW[tn], bE[te], acc[tn][te], 0, 0, 0);
    }
    #pragma unroll
    for (int tn = 0; tn < 4; ++tn) {
        float4 b4 = *(const float4*)(bias + cw + tn * 16 + l4 * 4);
        #pragma unroll
        for (int te = 0; te < 2; ++te) {
            int row = blk * 32 + te * 16 + l15;
            int col = cw + tn * 16 + l4 * 4;
            bf16x4 h;
            h[0] = (__bf16)(acc[tn][te][0] + b4.x);
            h[1] = (__bf16)(acc[tn][te][1] + b4.y);
            h[2] = (__bf16)(acc[tn][te][2] + b4.z);
            h[3] = (__bf16)(acc[tn][te][3] + b4.w);
            *(bf16x4*)(out + (size_t)row * 256 + col) = h;
        }
    }
}

// ---------------- counting sort by destination key = b*NN + s ---------------------
__global__ void k_hist(const int* __restrict__ eidx, unsigned* __restrict__ hist) {
    int e = blockIdx.x * 256 + threadIdx.x;
    int key = eidx[e] * NN + eidx[NE + e];
    atomicAdd(&hist[key], 1u);
}

__global__ void k_scan(const unsigned* __restrict__ hist, unsigned* __restrict__ cursor) {
    __shared__ unsigned tot[256];
    int tid = threadIdx.x;
    unsigned s = 0;
    for (int i = 0; i < 64; ++i) s += hist[tid * 64 + i];
    tot[tid] = s;
    __syncthreads();
    for (int d = 1; d < 256; d <<= 1) {
        unsigned v = (tid >= d) ? tot[tid - d] : 0u;
        __syncthreads();
        tot[tid] += v;
        __syncthreads();
    }
    unsigned run = (tid == 0) ? 0u : tot[tid - 1];
    for (int i = 0; i < 64; ++i) {
        int idx = tid * 64 + i;
        cursor[idx] = run;
        run += hist[idx];
    }
}

__global__ void k_perm(const int* __restrict__ eidx, unsigned* __restrict__ cursor,
                       int* __restrict__ perm) {
    int e = blockIdx.x * 256 + threadIdx.x;
    int key = eidx[e] * NN + eidx[NE + e];
    unsigned pos = atomicAdd(&cursor[key], 1u);
    perm[pos] = e;
}

// ------- edge logits: 64-edge tile, 8 waves, batched-ILP staging ------------------
__global__ __launch_bounds__(512, 4)
void edge_logits(const float* __restrict__ ev,
                 const int* __restrict__ eidx,
                 const __bf16* __restrict__ wbf,
                 const float* __restrict__ bkb,
                 const __bf16* __restrict__ qbf, const __bf16* __restrict__ kbf,
                 float* __restrict__ attn_ws) {
    __shared__ __bf16 evt[64 * 256];   // ev tile, then Ke tile (32 KB)
    __shared__ int sb[64], ss[64], st[64];
    char* lb = (char*)evt;
    int tid = threadIdx.x;
    int e0 = blockIdx.x * 64;

    // stage 64x256 f32 -> bf16 LDS: batch all 8 loads first (ILP), then cvt+write
    const float4* xs = (const float4*)(ev + (size_t)e0 * 256);
    float4 pf[8];
    #pragma unroll
    for (int kq = 0; kq < 8; ++kq)
        pf[kq] = xs[tid + kq * 512];
    if (tid < 64) {
        sb[tid] = eidx[e0 + tid];
        ss[tid] = eidx[NE + e0 + tid];
        st[tid] = eidx[2 * NE + e0 + tid];
    }
    #pragma unroll
    for (int kq = 0; kq < 8; ++kq) {
        int f = tid + kq * 512;
        int row = f >> 6, c4 = f & 63;
        bf16x4 h;
        h[0] = (__bf16)pf[kq].x; h[1] = (__bf16)pf[kq].y;
        h[2] = (__bf16)pf[kq].z; h[3] = (__bf16)pf[kq].w;
        int off = (row * 512 + c4 * 8) ^ ((row & 7) << 4);
        *(bf16x4*)(lb + off) = h;
    }
    __syncthreads();

    int w = tid >> 6, lane = tid & 63;   // w in 0..7
    int l15 = lane & 15, l4 = lane >> 4;
    int cw = w * 32;                     // each wave owns 32 output cols

    // Ke = ev @ Wk^T (swapped operands)
    const __bf16* WK = wbf + 65536;
    f32x4 acc[2][4] = {};
    for (int ks = 0; ks < 8; ++ks) {
        bf16x8 aW[2], bE[4];
        #pragma unroll
        for (int tn = 0; tn < 2; ++tn)
            aW[tn] = *(const bf16x8*)(WK + (size_t)(cw + tn * 16 + l15) * 256 + ks * 32 + l4 * 8);
        #pragma unroll
        for (int te = 0; te < 4; ++te) {
            int row = te * 16 + l15;
            int off = (row * 512 + ks * 64 + l4 * 16) ^ ((row & 7) << 4);
            bE[te] = *(const bf16x8*)(lb + off);
        }
        #pragma unroll
        for (int tn = 0; tn < 2; ++tn)
            #pragma unroll
            for (int te = 0; te < 4; ++te)
                acc[tn][te] = __builtin_amdgcn_mfma_f32_16x16x32_bf16(aW[tn], bE[te], acc[tn][te], 0, 0, 0);
    }
    __syncthreads();   // all MFMA reads of evt done

    // Ke (+bias) -> LDS bf16, edge-swizzled
    #pragma unroll
    for (int tn = 0; tn < 2; ++tn) {
        float4 b4 = *(const float4*)(bkb + cw + tn * 16 + l4 * 4);
        #pragma unroll
        for (int te = 0; te < 4; ++te) {
            int edge = te * 16 + l15;
            int colb = (cw + tn * 16 + l4 * 4) * 2;
            bf16x4 h;
            h[0] = (__bf16)(acc[tn][te][0] + b4.x);
            h[1] = (__bf16)(acc[tn][te][1] + b4.y);
            h[2] = (__bf16)(acc[tn][te][2] + b4.z);
            h[3] = (__bf16)(acc[tn][te][3] + b4.w);
            int off = (edge * 512 + colb) ^ ((edge & 7) << 4);
            *(bf16x4*)(lb + off) = h;
        }
    }
    __syncthreads();

    // logits + softmax; half-wave per edge, 8 edges per wave
    int cl = lane & 31, eh = lane >> 5;
    #pragma unroll
    for (int it = 0; it < 4; ++it) {
        int e = w * 8 + it * 2 + eh;
        int b_ = sb[e], s_ = ss[e], t_ = st[e];
        bf16x8 qv = *(const bf16x8*)(qbf + ((size_t)b_ * NN + s_) * 256 + cl * 8);
        bf16x8 kv = *(const bf16x8*)(kbf + ((size_t)b_ * NN + t_) * 256 + cl * 8);
        int off = (e * 512 + cl * 16) ^ ((e & 7) << 4);
        bf16x8 kev = *(const bf16x8*)(lb + off);
        float val = 0.f;
        #pragma unroll
        for (int j = 0; j < 8; ++j)
            val += (float)qv[j] * ((float)kv[j] + (float)kev[j]);
        val += __shfl_xor(val, 1);
        val += __shfl_xor(val, 2);          // 4-lane group = one head (D=32)
        val *= 0.17677669529663687f;
        float mx = val;
        mx = fmaxf(mx, __shfl_xor(mx, 4));
        mx = fmaxf(mx, __shfl_xor(mx, 8));
        mx = fmaxf(mx, __shfl_xor(mx, 16));
        float ex = __expf(val - mx);
        float s4 = ex;
        s4 += __shfl_xor(s4, 4);
        s4 += __shfl_xor(s4, 8);
        s4 += __shfl_xor(s4, 16);           // butterfly hits each head exactly once
        float a = ex / s4;
        if ((cl & 3) == 0)
            attn_ws[(size_t)(e0 + e) * 8 + (cl >> 2)] = a;
    }
}

// ------- edge scatter: sorted order, 64-edge tile, 8 waves, batched staging -------
__global__ __launch_bounds__(512, 4)
void edge_scatter2(const float* __restrict__ ev,
                   const int* __restrict__ eidx,
                   const __bf16* __restrict__ wbf,
                   const float* __restrict__ beb,
                   const __bf16* __restrict__ vbf,
                   const float* __restrict__ attn_ws,
                   const int* __restrict__ perm,
                   float* __restrict__ out) {
    __shared__ __bf16 evt[64 * 256];
    __shared__ int pe[64], sb[64], ss[64], st[64];
    char* lb = (char*)evt;
    int tid = threadIdx.x;
    int p0 = blockIdx.x * 64;

    if (tid < 64) {
        int e = perm[p0 + tid];
        pe[tid] = e;
        sb[tid] = eidx[e];
        ss[tid] = eidx[NE + e];
        st[tid] = eidx[2 * NE + e];
    }
    __syncthreads();

    // stage gathered ev rows: batch all 8 loads first, then cvt+write
    float4 pf[8];
    #pragma unroll
    for (int kq = 0; kq < 8; ++kq) {
        int f = tid + kq * 512;
        int row = f >> 6, c4 = f & 63;
        pf[kq] = ((const float4*)(ev + (size_t)pe[row] * 256))[c4];
    }
    #pragma unroll
    for (int kq = 0; kq < 8; ++kq) {
        int f = tid + kq * 512;
        int row = f >> 6, c4 = f & 63;
        bf16x4 h;
        h[0] = (__bf16)pf[kq].x; h[1] = (__bf16)pf[kq].y;
        h[2] = (__bf16)pf[kq].z; h[3] = (__bf16)pf[kq].w;
        int off = (row * 512 + c4 * 8) ^ ((row & 7) << 4);
        *(bf16x4*)(lb + off) = h;
    }
    __syncthreads();

    int w = tid >> 6, lane = tid & 63;
    int l15 = lane & 15, l4 = lane >> 4;
    int cw = w * 32;

    const __bf16* WE = wbf + 3 * 65536;
    f32x4 acc[2][4] = {};
    for (int ks = 0; ks < 8; ++ks) {
        bf16x8 aW[2], bE[4];
        #pragma unroll
        for (int tn = 0; tn < 2; ++tn)
            aW[tn] = *(const bf16x8*)(WE + (size_t)(cw + tn * 16 + l15) * 256 + ks * 32 + l4 * 8);
        #pragma unroll
        for (int te = 0; te < 4; ++te) {
            int row = te * 16 + l15;
            int off = (row * 512 + ks * 64 + l4 * 16) ^ ((row & 7) << 4);
            bE[te] = *(const bf16x8*)(lb + off);
        }
        #pragma unroll
        for (int tn = 0; tn < 2; ++tn)
            #pragma unroll
            for (int te = 0; te < 4; ++te)
                acc[tn][te] = __builtin_amdgcn_mfma_f32_16x16x32_bf16(aW[tn], bE[te], acc[tn][te], 0, 0, 0);
    }
    __syncthreads();

    // Ve (+bias) -> LDS bf16, edge-swizzled
    #pragma unroll
    for (int tn = 0; tn < 2; ++tn) {
        float4 b4 = *(const float4*)(beb + cw + tn * 16 + l4 * 4);
        #pragma unroll
        for (int te = 0; te < 4; ++te) {
            int edge = te * 16 + l15;
            int colb = (cw + tn * 16 + l4 * 4) * 2;
            bf16x4 h;
            h[0] = (__bf16)(acc[tn][te][0] + b4.x);
            h[1] = (__bf16)(acc[tn][te][1] + b4.y);
            h[2] = (__bf16)(acc[tn][te][2] + b4.z);
            h[3] = (__bf16)(acc[tn][te][3] + b4.w);
            int off = (edge * 512 + colb) ^ ((edge & 7) << 4);
            *(bf16x4*)(lb + off) = h;
        }
    }
    __syncthreads();

    // wave-per-edge tail; 8 sorted edges/wave; run-length accumulate in regs
    float a0 = 0.f, a1 = 0.f, a2 = 0.f, a3 = 0.f;
    int havekey = -1;
    size_t obase = 0;
    #pragma unroll
    for (int it = 0; it < 8; ++it) {
        int e = w * 8 + it;
        int ge = pe[e];
        int b_ = sb[e], s_ = ss[e], t_ = st[e];
        const __bf16* vrow = vbf + ((size_t)b_ * NN + t_) * 256;
        const float* arow = attn_ws + (size_t)ge * 8;
        int swz = (e & 7) << 4;
        float c0, c1, c2, c3;
        {
            float att, vv, vev;
            int col, off;
            col = lane;             att = arow[0 + (lane >> 5)];
            vv = (float)vrow[col];  off = (e * 512 + col * 2) ^ swz;
            vev = (float)*(const __bf16*)(lb + off); c0 = att * (vv + vev);
            col = 64 + lane;        att = arow[2 + (lane >> 5)];
            vv = (float)vrow[col];  off = (e * 512 + col * 2) ^ swz;
            vev = (float)*(const __bf16*)(lb + off); c1 = att * (vv + vev);
            col = 128 + lane;       att = arow[4 + (lane >> 5)];
            vv = (float)vrow[col];  off = (e * 512 + col * 2) ^ swz;
            vev = (float)*(const __bf16*)(lb + off); c2 = att * (vv + vev);
            col = 192 + lane;       att = arow[6 + (lane >> 5)];
            vv = (float)vrow[col];  off = (e * 512 + col * 2) ^ swz;
            vev = (float)*(const __bf16*)(lb + off); c3 = att * (vv + vev);
        }
        int key = __builtin_amdgcn_readfirstlane(b_ * NN + s_);
        if (key != havekey) {
            if (havekey >= 0) {
                float* orow = out + obase;
                unsafeAtomicAdd(orow + lane, a0);
                unsafeAtomicAdd(orow + 64 + lane, a1);
                unsafeAtomicAdd(orow + 128 + lane, a2);
                unsafeAtomicAdd(orow + 192 + lane, a3);
            }
            a0 = c0; a1 = c1; a2 = c2; a3 = c3;
            havekey = key;
            obase = (size_t)key * 256;
        } else {
            a0 += c0; a1 += c1; a2 += c2; a3 += c3;
        }
    }
    if (havekey >= 0) {
        float* orow = out + obase;
        unsafeAtomicAdd(orow + lane, a0);
        unsafeAtomicAdd(orow + 64 + lane, a1);
        unsafeAtomicAdd(orow + 128 + lane, a2);
        unsafeAtomicAdd(orow + 192 + lane, a3);
    }
}

extern "C" void kernel_launch(void* const* d_in, const int* in_sizes, int n_in,
                              void* d_out, int out_size, void* d_ws, size_t ws_size,
                              hipStream_t stream) {
    const float* node_states = (const float*)d_in[0];
    const int*   eidx        = (const int*)d_in[1];
    const float* ev          = (const float*)d_in[2];
    const float* Wq          = (const float*)d_in[3];
    const float* bq          = (const float*)d_in[4];
    const float* Wk          = (const float*)d_in[5];
    const float* bk          = (const float*)d_in[6];
    const float* Wv          = (const float*)d_in[7];
    const float* bv          = (const float*)d_in[8];
    const float* We          = (const float*)d_in[9];
    const float* be          = (const float*)d_in[10];
    float* out = (float*)d_out;

    char* ws = (char*)d_ws;
    __bf16*   qbf     = (__bf16*)ws;                   // 8.39 MB
    __bf16*   kbf     = (__bf16*)(ws + 8388608);       // 8.39 MB
    __bf16*   vbf     = (__bf16*)(ws + 16777216);      // 8.39 MB
    float*    attn_ws = (float*)(ws + 25165824);       // 8.39 MB
    __bf16*   wbf     = (__bf16*)(ws + 33554432);      // 0.5 MB
    unsigned* hist    = (unsigned*)(ws + 34078720);    // 64 KB
    unsigned* cursor  = (unsigned*)(ws + 34144256);    // 64 KB
    int*      perm    = (int*)(ws + 34209792);         // 1 MB

    hipMemsetAsync(d_out, 0, (size_t)out_size * sizeof(float), stream);
    hipMemsetAsync(hist, 0, 16384 * sizeof(unsigned), stream);
    conv_weights<<<1024, 256, 0, stream>>>(Wq, Wk, Wv, We, wbf);
    qkv_gemm<<<dim3(512, 3), 256, 0, stream>>>(node_states, wbf, bq, bk, bv, qbf, kbf, vbf);
    k_hist<<<1024, 256, 0, stream>>>(eidx, hist);
    k_scan<<<1, 256, 0, stream>>>(hist, cursor);
    k_perm<<<1024, 256, 0, stream>>>(eidx, cursor, perm);
    edge_logits<<<4096, 512, 0, stream>>>(ev, eidx, wbf, bk, qbf, kbf, attn_ws);
    edge_scatter2<<<4096, 512, 0, stream>>>(ev, eidx, wbf, be, vbf, attn_ws, perm, out);
}

// Round 17
// 291.665 us; speedup vs baseline: 1.8942x; 1.0733x over previous
//
#include <hip/hip_runtime.h>
#include <hip/hip_bf16.h>

#define HID 256
#define NN 8192
#define NE 262144

typedef float f32x4 __attribute__((ext_vector_type(4)));
typedef __bf16 bf16x8 __attribute__((ext_vector_type(8)));
typedef __bf16 bf16x4 __attribute__((ext_vector_type(4)));

// ---------------- weight conversion: f32 -> bf16, [Wq][Wk][Wv][We] ----------------
__global__ void conv_weights(const float* __restrict__ wq, const float* __restrict__ wk,
                             const float* __restrict__ wv, const float* __restrict__ we,
                             __bf16* __restrict__ o) {
    int i = blockIdx.x * 256 + threadIdx.x;
    const float* srcs[4] = {wq, wk, wv, we};
    int m = i >> 16;
    int j = i & 65535;
    o[i] = (__bf16)srcs[m][j];
}

// ---------------- QKV projection: 32-row tiles, blockIdx.y = which GEMM -----------
__global__ __launch_bounds__(256, 6)
void qkv_gemm(const float* __restrict__ x,
              const __bf16* __restrict__ wbf,
              const float* __restrict__ bq, const float* __restrict__ bk,
              const float* __restrict__ bv,
              __bf16* __restrict__ qbf, __bf16* __restrict__ kbf,
              __bf16* __restrict__ vbf) {
    __shared__ __bf16 xt[32 * 256];
    char* lb = (char*)xt;
    int tid = threadIdx.x;
    int blk = blockIdx.x;
    int m = blockIdx.y;

    const float4* xs = (const float4*)(x + (size_t)blk * 32 * 256);
    #pragma unroll
    for (int kq = 0; kq < 8; ++kq) {
        int f = tid + kq * 256;
        int row = f >> 6, c4 = f & 63;
        float4 v = xs[f];
        bf16x4 h;
        h[0] = (__bf16)v.x; h[1] = (__bf16)v.y; h[2] = (__bf16)v.z; h[3] = (__bf16)v.w;
        int off = (row * 512 + c4 * 8) ^ ((row & 7) << 4);
        *(bf16x4*)(lb + off) = h;
    }
    __syncthreads();

    int w = tid >> 6, lane = tid & 63;
    int l15 = lane & 15, l4 = lane >> 4;
    int cw = w * 64;
    const float* bias = (m == 0) ? bq : ((m == 1) ? bk : bv);
    __bf16* out = (m == 0) ? qbf : ((m == 1) ? kbf : vbf);

    const __bf16* W = wbf + (size_t)m * 65536;
    f32x4 acc[4][2] = {};
    for (int ks = 0; ks < 8; ++ks) {
        bf16x8 aW[4], bE[2];
        #pragma unroll
        for (int tn = 0; tn < 4; ++tn)
            aW[tn] = *(const bf16x8*)(W + (size_t)(cw + tn * 16 + l15) * 256 + ks * 32 + l4 * 8);
        #pragma unroll
        for (int te = 0; te < 2; ++te) {
            int row = te * 16 + l15;
            int off = (row * 512 + ks * 64 + l4 * 16) ^ ((row & 7) << 4);
            bE[te] = *(const bf16x8*)(lb + off);
        }
        #pragma unroll
        for (int tn = 0; tn < 4; ++tn)
            #pragma unroll
            for (int te = 0; te < 2; ++te)
                acc[tn][te] = __builtin_amdgcn_mfma_f32_16x16x32_bf16(aW[tn], bE[te], acc[tn][te], 0, 0, 0);
    }
    #pragma unroll
    for (int tn = 0; tn < 4; ++tn) {
        float4 b4 = *(const float4*)(bias + cw + tn * 16 + l4 * 4);
        #pragma unroll
        for (int te = 0; te < 2; ++te) {
            int row = blk * 32 + te * 16 + l15;
            int col = cw + tn * 16 + l4 * 4;
            bf16x4 h;
            h[0] = (__bf16)(acc[tn][te][0] + b4.x);
            h[1] = (__bf16)(acc[tn][te][1] + b4.y);
            h[2] = (__bf16)(acc[tn][te][2] + b4.z);
            h[3] = (__bf16)(acc[tn][te][3] + b4.w);
            *(bf16x4*)(out + (size_t)row * 256 + col) = h;
        }
    }
}

// ---------------- counting sort by destination key = b*NN + s ---------------------
__global__ void k_hist(const int* __restrict__ eidx, unsigned* __restrict__ hist) {
    int e = blockIdx.x * 256 + threadIdx.x;
    int key = eidx[e] * NN + eidx[NE + e];
    atomicAdd(&hist[key], 1u);
}

__global__ void k_scan(const unsigned* __restrict__ hist, unsigned* __restrict__ cursor) {
    __shared__ unsigned tot[256];
    int tid = threadIdx.x;
    unsigned s = 0;
    for (int i = 0; i < 64; ++i) s += hist[tid * 64 + i];
    tot[tid] = s;
    __syncthreads();
    for (int d = 1; d < 256; d <<= 1) {
        unsigned v = (tid >= d) ? tot[tid - d] : 0u;
        __syncthreads();
        tot[tid] += v;
        __syncthreads();
    }
    unsigned run = (tid == 0) ? 0u : tot[tid - 1];
    for (int i = 0; i < 64; ++i) {
        int idx = tid * 64 + i;
        cursor[idx] = run;
        run += hist[idx];
    }
}

__global__ void k_perm(const int* __restrict__ eidx, unsigned* __restrict__ cursor,
                       int* __restrict__ perm) {
    int e = blockIdx.x * 256 + threadIdx.x;
    int key = eidx[e] * NN + eidx[NE + e];
    unsigned pos = atomicAdd(&cursor[key], 1u);
    perm[pos] = e;
}

// ------- edge logits: 128-edge tile, 8 waves, batched-ILP staging -----------------
__global__ __launch_bounds__(512, 2)
void edge_logits(const float* __restrict__ ev,
                 const int* __restrict__ eidx,
                 const __bf16* __restrict__ wbf,
                 const float* __restrict__ bkb,
                 const __bf16* __restrict__ qbf, const __bf16* __restrict__ kbf,
                 float* __restrict__ attn_ws) {
    __shared__ __bf16 evt[128 * 256];  // ev tile, then Ke tile (64 KB)
    __shared__ int sb[128], ss[128], st[128];
    char* lb = (char*)evt;
    int tid = threadIdx.x;
    int e0 = blockIdx.x * 128;

    // stage 128x256 f32 -> bf16 LDS: batch all 16 loads first (ILP), then cvt+write
    const float4* xs = (const float4*)(ev + (size_t)e0 * 256);
    float4 pf[16];
    #pragma unroll
    for (int kq = 0; kq < 16; ++kq)
        pf[kq] = xs[tid + kq * 512];
    if (tid < 128) {
        sb[tid] = eidx[e0 + tid];
        ss[tid] = eidx[NE + e0 + tid];
        st[tid] = eidx[2 * NE + e0 + tid];
    }
    #pragma unroll
    for (int kq = 0; kq < 16; ++kq) {
        int f = tid + kq * 512;
        int row = f >> 6, c4 = f & 63;
        bf16x4 h;
        h[0] = (__bf16)pf[kq].x; h[1] = (__bf16)pf[kq].y;
        h[2] = (__bf16)pf[kq].z; h[3] = (__bf16)pf[kq].w;
        int off = (row * 512 + c4 * 8) ^ ((row & 7) << 4);
        *(bf16x4*)(lb + off) = h;
    }
    __syncthreads();

    int w = tid >> 6, lane = tid & 63;   // w in 0..7
    int l15 = lane & 15, l4 = lane >> 4;
    int cw = w * 32;                     // each wave owns 32 output cols

    // Ke = ev @ Wk^T (swapped operands), 8 edge-subtiles
    const __bf16* WK = wbf + 65536;
    f32x4 acc[2][8] = {};
    for (int ks = 0; ks < 8; ++ks) {
        bf16x8 aW[2], bE[8];
        #pragma unroll
        for (int tn = 0; tn < 2; ++tn)
            aW[tn] = *(const bf16x8*)(WK + (size_t)(cw + tn * 16 + l15) * 256 + ks * 32 + l4 * 8);
        #pragma unroll
        for (int te = 0; te < 8; ++te) {
            int row = te * 16 + l15;
            int off = (row * 512 + ks * 64 + l4 * 16) ^ ((row & 7) << 4);
            bE[te] = *(const bf16x8*)(lb + off);
        }
        #pragma unroll
        for (int tn = 0; tn < 2; ++tn)
            #pragma unroll
            for (int te = 0; te < 8; ++te)
                acc[tn][te] = __builtin_amdgcn_mfma_f32_16x16x32_bf16(aW[tn], bE[te], acc[tn][te], 0, 0, 0);
    }
    __syncthreads();   // all MFMA reads of evt done

    // Ke (+bias) -> LDS bf16, edge-swizzled
    #pragma unroll
    for (int tn = 0; tn < 2; ++tn) {
        float4 b4 = *(const float4*)(bkb + cw + tn * 16 + l4 * 4);
        #pragma unroll
        for (int te = 0; te < 8; ++te) {
            int edge = te * 16 + l15;
            int colb = (cw + tn * 16 + l4 * 4) * 2;
            bf16x4 h;
            h[0] = (__bf16)(acc[tn][te][0] + b4.x);
            h[1] = (__bf16)(acc[tn][te][1] + b4.y);
            h[2] = (__bf16)(acc[tn][te][2] + b4.z);
            h[3] = (__bf16)(acc[tn][te][3] + b4.w);
            int off = (edge * 512 + colb) ^ ((edge & 7) << 4);
            *(bf16x4*)(lb + off) = h;
        }
    }
    __syncthreads();

    // logits + softmax; half-wave per edge, 16 edges per wave
    int cl = lane & 31, eh = lane >> 5;
    #pragma unroll
    for (int it = 0; it < 8; ++it) {
        int e = w * 16 + it * 2 + eh;
        int b_ = sb[e], s_ = ss[e], t_ = st[e];
        bf16x8 qv = *(const bf16x8*)(qbf + ((size_t)b_ * NN + s_) * 256 + cl * 8);
        bf16x8 kv = *(const bf16x8*)(kbf + ((size_t)b_ * NN + t_) * 256 + cl * 8);
        int off = (e * 512 + cl * 16) ^ ((e & 7) << 4);
        bf16x8 kev = *(const bf16x8*)(lb + off);
        float val = 0.f;
        #pragma unroll
        for (int j = 0; j < 8; ++j)
            val += (float)qv[j] * ((float)kv[j] + (float)kev[j]);
        val += __shfl_xor(val, 1);
        val += __shfl_xor(val, 2);          // 4-lane group = one head (D=32)
        val *= 0.17677669529663687f;
        float mx = val;
        mx = fmaxf(mx, __shfl_xor(mx, 4));
        mx = fmaxf(mx, __shfl_xor(mx, 8));
        mx = fmaxf(mx, __shfl_xor(mx, 16));
        float ex = __expf(val - mx);
        float s4 = ex;
        s4 += __shfl_xor(s4, 4);
        s4 += __shfl_xor(s4, 8);
        s4 += __shfl_xor(s4, 16);           // butterfly hits each head exactly once
        float a = ex / s4;
        if ((cl & 3) == 0)
            attn_ws[(size_t)(e0 + e) * 8 + (cl >> 2)] = a;
    }
}

// ------- edge scatter: sorted order, 128-edge tile, 8 waves, run-length tail ------
__global__ __launch_bounds__(512, 2)
void edge_scatter2(const float* __restrict__ ev,
                   const int* __restrict__ eidx,
                   const __bf16* __restrict__ wbf,
                   const float* __restrict__ beb,
                   const __bf16* __restrict__ vbf,
                   const float* __restrict__ attn_ws,
                   const int* __restrict__ perm,
                   float* __restrict__ out) {
    __shared__ __bf16 evt[128 * 256];  // 64 KB
    __shared__ int pe[128], sb[128], ss[128], st[128];
    char* lb = (char*)evt;
    int tid = threadIdx.x;
    int p0 = blockIdx.x * 128;

    if (tid < 128) {
        int e = perm[p0 + tid];
        pe[tid] = e;
        sb[tid] = eidx[e];
        ss[tid] = eidx[NE + e];
        st[tid] = eidx[2 * NE + e];
    }
    __syncthreads();

    // stage gathered ev rows: batch all 16 loads first, then cvt+write
    float4 pf[16];
    #pragma unroll
    for (int kq = 0; kq < 16; ++kq) {
        int f = tid + kq * 512;
        int row = f >> 6, c4 = f & 63;
        pf[kq] = ((const float4*)(ev + (size_t)pe[row] * 256))[c4];
    }
    #pragma unroll
    for (int kq = 0; kq < 16; ++kq) {
        int f = tid + kq * 512;
        int row = f >> 6, c4 = f & 63;
        bf16x4 h;
        h[0] = (__bf16)pf[kq].x; h[1] = (__bf16)pf[kq].y;
        h[2] = (__bf16)pf[kq].z; h[3] = (__bf16)pf[kq].w;
        int off = (row * 512 + c4 * 8) ^ ((row & 7) << 4);
        *(bf16x4*)(lb + off) = h;
    }
    __syncthreads();

    int w = tid >> 6, lane = tid & 63;
    int l15 = lane & 15, l4 = lane >> 4;
    int cw = w * 32;

    const __bf16* WE = wbf + 3 * 65536;
    f32x4 acc[2][8] = {};
    for (int ks = 0; ks < 8; ++ks) {
        bf16x8 aW[2], bE[8];
        #pragma unroll
        for (int tn = 0; tn < 2; ++tn)
            aW[tn] = *(const bf16x8*)(WE + (size_t)(cw + tn * 16 + l15) * 256 + ks * 32 + l4 * 8);
        #pragma unroll
        for (int te = 0; te < 8; ++te) {
            int row = te * 16 + l15;
            int off = (row * 512 + ks * 64 + l4 * 16) ^ ((row & 7) << 4);
            bE[te] = *(const bf16x8*)(lb + off);
        }
        #pragma unroll
        for (int tn = 0; tn < 2; ++tn)
            #pragma unroll
            for (int te = 0; te < 8; ++te)
                acc[tn][te] = __builtin_amdgcn_mfma_f32_16x16x32_bf16(aW[tn], bE[te], acc[tn][te], 0, 0, 0);
    }
    __syncthreads();

    // Ve (+bias) -> LDS bf16, edge-swizzled
    #pragma unroll
    for (int tn = 0; tn < 2; ++tn) {
        float4 b4 = *(const float4*)(beb + cw + tn * 16 + l4 * 4);
        #pragma unroll
        for (int te = 0; te < 8; ++te) {
            int edge = te * 16 + l15;
            int colb = (cw + tn * 16 + l4 * 4) * 2;
            bf16x4 h;
            h[0] = (__bf16)(acc[tn][te][0] + b4.x);
            h[1] = (__bf16)(acc[tn][te][1] + b4.y);
            h[2] = (__bf16)(acc[tn][te][2] + b4.z);
            h[3] = (__bf16)(acc[tn][te][3] + b4.w);
            int off = (edge * 512 + colb) ^ ((edge & 7) << 4);
            *(bf16x4*)(lb + off) = h;
        }
    }
    __syncthreads();

    // wave-per-edge tail; 16 sorted edges/wave; run-length accumulate in regs
    float a0 = 0.f, a1 = 0.f, a2 = 0.f, a3 = 0.f;
    int havekey = -1;
    size_t obase = 0;
    #pragma unroll
    for (int it = 0; it < 16; ++it) {
        int e = w * 16 + it;
        int ge = pe[e];
        int b_ = sb[e], s_ = ss[e], t_ = st[e];
        const __bf16* vrow = vbf + ((size_t)b_ * NN + t_) * 256;
        const float* arow = attn_ws + (size_t)ge * 8;
        int swz = (e & 7) << 4;
        float c0, c1, c2, c3;
        {
            float att, vv, vev;
            int col, off;
            col = lane;             att = arow[0 + (lane >> 5)];
            vv = (float)vrow[col];  off = (e * 512 + col * 2) ^ swz;
            vev = (float)*(const __bf16*)(lb + off); c0 = att * (vv + vev);
            col = 64 + lane;        att = arow[2 + (lane >> 5)];
            vv = (float)vrow[col];  off = (e * 512 + col * 2) ^ swz;
            vev = (float)*(const __bf16*)(lb + off); c1 = att * (vv + vev);
            col = 128 + lane;       att = arow[4 + (lane >> 5)];
            vv = (float)vrow[col];  off = (e * 512 + col * 2) ^ swz;
            vev = (float)*(const __bf16*)(lb + off); c2 = att * (vv + vev);
            col = 192 + lane;       att = arow[6 + (lane >> 5)];
            vv = (float)vrow[col];  off = (e * 512 + col * 2) ^ swz;
            vev = (float)*(const __bf16*)(lb + off); c3 = att * (vv + vev);
        }
        int key = __builtin_amdgcn_readfirstlane(b_ * NN + s_);
        if (key != havekey) {
            if (havekey >= 0) {
                float* orow = out + obase;
                unsafeAtomicAdd(orow + lane, a0);
                unsafeAtomicAdd(orow + 64 + lane, a1);
                unsafeAtomicAdd(orow + 128 + lane, a2);
                unsafeAtomicAdd(orow + 192 + lane, a3);
            }
            a0 = c0; a1 = c1; a2 = c2; a3 = c3;
            havekey = key;
            obase = (size_t)key * 256;
        } else {
            a0 += c0; a1 += c1; a2 += c2; a3 += c3;
        }
    }
    if (havekey >= 0) {
        float* orow = out + obase;
        unsafeAtomicAdd(orow + lane, a0);
        unsafeAtomicAdd(orow + 64 + lane, a1);
        unsafeAtomicAdd(orow + 128 + lane, a2);
        unsafeAtomicAdd(orow + 192 + lane, a3);
    }
}

extern "C" void kernel_launch(void* const* d_in, const int* in_sizes, int n_in,
                              void* d_out, int out_size, void* d_ws, size_t ws_size,
                              hipStream_t stream) {
    const float* node_states = (const float*)d_in[0];
    const int*   eidx        = (const int*)d_in[1];
    const float* ev          = (const float*)d_in[2];
    const float* Wq          = (const float*)d_in[3];
    const float* bq          = (const float*)d_in[4];
    const float* Wk          = (const float*)d_in[5];
    const float* bk          = (const float*)d_in[6];
    const float* Wv          = (const float*)d_in[7];
    const float* bv          = (const float*)d_in[8];
    const float* We          = (const float*)d_in[9];
    const float* be          = (const float*)d_in[10];
    float* out = (float*)d_out;

    char* ws = (char*)d_ws;
    __bf16*   qbf     = (__bf16*)ws;                   // 8.39 MB
    __bf16*   kbf     = (__bf16*)(ws + 8388608);       // 8.39 MB
    __bf16*   vbf     = (__bf16*)(ws + 16777216);      // 8.39 MB
    float*    attn_ws = (float*)(ws + 25165824);       // 8.39 MB
    __bf16*   wbf     = (__bf16*)(ws + 33554432);      // 0.5 MB
    unsigned* hist    = (unsigned*)(ws + 34078720);    // 64 KB
    unsigned* cursor  = (unsigned*)(ws + 34144256);    // 64 KB
    int*      perm    = (int*)(ws + 34209792);         // 1 MB

    hipMemsetAsync(d_out, 0, (size_t)out_size * sizeof(float), stream);
    hipMemsetAsync(hist, 0, 16384 * sizeof(unsigned), stream);
    conv_weights<<<1024, 256, 0, stream>>>(Wq, Wk, Wv, We, wbf);
    qkv_gemm<<<dim3(512, 3), 256, 0, stream>>>(node_states, wbf, bq, bk, bv, qbf, kbf, vbf);
    k_hist<<<1024, 256, 0, stream>>>(eidx, hist);
    k_scan<<<1, 256, 0, stream>>>(hist, cursor);
    k_perm<<<1024, 256, 0, stream>>>(eidx, cursor, perm);
    edge_logits<<<2048, 512, 0, stream>>>(ev, eidx, wbf, bk, qbf, kbf, attn_ws);
    edge_scatter2<<<2048, 512, 0, stream>>>(ev, eidx, wbf, be, vbf, attn_ws, perm, out);
}